// Round 1
// baseline (106.947 us; speedup 1.0000x reference)
//
#include <hip/hip_runtime.h>

// Net_24395414241687: the reference ends with
//   jax.nn.log_softmax(g @ fc2W + fc2b, axis=1)   where the argument is (1024, 1).
// log_softmax over a singleton axis is identically 0.0 (x - logsumexp([x]) == 0,
// computed exactly by the max-shift formulation). All upstream work (both NNConv
// layers, pooling, FC layers) is dead code. The correct output is zeros(1024).
//
// d_out is re-poisoned to 0xAA before every timed launch, so we must write the
// zeros on every call.

__global__ void write_zeros_kernel(float* __restrict__ out, int n) {
    int i = blockIdx.x * blockDim.x + threadIdx.x;
    if (i < n) out[i] = 0.0f;
}

extern "C" void kernel_launch(void* const* d_in, const int* in_sizes, int n_in,
                              void* d_out, int out_size, void* d_ws, size_t ws_size,
                              hipStream_t stream) {
    (void)d_in; (void)in_sizes; (void)n_in; (void)d_ws; (void)ws_size;
    float* out = (float*)d_out;
    int n = out_size;  // 1024 (G graphs x 1 class), float32
    write_zeros_kernel<<<(n + 255) / 256, 256, 0, stream>>>(out, n);
}